// Round 1
// baseline (491.227 us; speedup 1.0000x reference)
//
#include <hip/hip_runtime.h>

#define HH 128
#define WW 128
#define HWSZ (HH*WW)
#define NB 4
#define CIN 64
#define COUT 64
#define KK 9

// ---------------- weight repack ----------------
// wrep1: [65][9][27]  (o: 0..17 = offset_w, 18..26 = mask_w)
// wrep3: [9][64][64]  wrep3[(k*64+c)*64+o] = weight[o][c][k]
__global__ void repack_kernel(const float* __restrict__ offset_w,
                              const float* __restrict__ mask_w,
                              const float* __restrict__ weight,
                              float* __restrict__ wrep1,
                              float* __restrict__ wrep3) {
    int idx = blockIdx.x * 256 + threadIdx.x;
    if (idx < 65 * 9 * 27) {
        int o = idx % 27;
        int t = (idx / 27) % 9;
        int c = idx / (27 * 9);
        float v = (o < 18) ? offset_w[(o * 65 + c) * 9 + t]
                           : mask_w[((o - 18) * 65 + c) * 9 + t];
        wrep1[idx] = v;
    }
    if (idx < 9 * 64 * 64) {
        int o = idx % 64;
        int c = (idx / 64) % 64;
        int k = idx / (64 * 64);
        wrep3[idx] = weight[(o * 64 + c) * 9 + k];
    }
}

// ---------------- offset + mask conv (65ch in, 27ch out, 3x3, pad 1) ----------------
__global__ __launch_bounds__(256) void conv_offset_mask(
    const float* __restrict__ input, const float* __restrict__ mask_in,
    const float* __restrict__ wrep1, const float* __restrict__ offset_b,
    const float* __restrict__ mask_b,
    float* __restrict__ off_out, float* __restrict__ mm_out)
{
    int tx = threadIdx.x & 15, ty = threadIdx.x >> 4;
    int j = (blockIdx.x & 7) * 16 + tx;
    int i = ((blockIdx.x >> 3) & 7) * 16 + ty;
    int b = blockIdx.x >> 6;

    float acc[27];
#pragma unroll
    for (int o = 0; o < 18; ++o) acc[o] = offset_b[o];
#pragma unroll
    for (int o = 0; o < 9; ++o) acc[18 + o] = mask_b[o];

    // prefetch patch for c=0
    float patch[9];
    {
        const float* xp = input + (size_t)(b * 64) * HWSZ;
#pragma unroll
        for (int dy = 0; dy < 3; ++dy) {
            int yy = i + dy - 1;
#pragma unroll
            for (int dx = 0; dx < 3; ++dx) {
                int xx = j + dx - 1;
                bool ok = (yy >= 0) && (yy < HH) && (xx >= 0) && (xx < WW);
                patch[dy * 3 + dx] = ok ? xp[yy * WW + xx] : 0.f;
            }
        }
    }

    for (int c = 0; c < 65; ++c) {
        float cur[9];
#pragma unroll
        for (int t = 0; t < 9; ++t) cur[t] = patch[t];
        if (c < 64) {
            const float* xp = (c + 1 < 64) ? (input + (size_t)(b * 64 + c + 1) * HWSZ)
                                           : (mask_in + (size_t)b * HWSZ);
#pragma unroll
            for (int dy = 0; dy < 3; ++dy) {
                int yy = i + dy - 1;
#pragma unroll
                for (int dx = 0; dx < 3; ++dx) {
                    int xx = j + dx - 1;
                    bool ok = (yy >= 0) && (yy < HH) && (xx >= 0) && (xx < WW);
                    patch[dy * 3 + dx] = ok ? xp[yy * WW + xx] : 0.f;
                }
            }
        }
        const float* wp = wrep1 + c * 9 * 27;
#pragma unroll
        for (int t = 0; t < 9; ++t) {
            float pv = cur[t];
#pragma unroll
            for (int o = 0; o < 27; ++o)
                acc[o] = fmaf(pv, wp[t * 27 + o], acc[o]);
        }
    }

    int p = i * WW + j;
#pragma unroll
    for (int o = 0; o < 18; ++o)
        off_out[(b * 18 + o) * HWSZ + p] = acc[o];
#pragma unroll
    for (int o = 0; o < 9; ++o) {
        float s = 1.f / (1.f + __expf(-acc[18 + o]));
        mm_out[(b * 9 + o) * HWSZ + p] = s;
    }
}

// ---------------- update_mask: clip(64 * sum_k bilinear(mask_in), 0, 1) ----------------
__global__ __launch_bounds__(256) void update_mask_kernel(
    const float* __restrict__ mask_in, const float* __restrict__ off,
    float* __restrict__ upd)
{
    int g = blockIdx.x * 256 + threadIdx.x;   // over NB*HWSZ
    int p = g & (HWSZ - 1);
    int b = g >> 14;
    int i = p >> 7, j = p & 127;
    const float* mp = mask_in + (size_t)b * HWSZ;
    float sum = 0.f;
#pragma unroll
    for (int k = 0; k < KK; ++k) {
        float dy = off[(b * 18 + 2 * k) * HWSZ + p];
        float dx = off[(b * 18 + 2 * k + 1) * HWSZ + p];
        float py = dy + (float)(k / 3 + i - 1);
        float px = dx + (float)(k % 3 + j - 1);
        float fy = floorf(py), fx = floorf(px);
        float wy = py - fy, wx = px - fx;
        int y0 = (int)fy, x0 = (int)fx;
        int y1 = y0 + 1, x1 = x0 + 1;
        bool vy0 = (y0 >= 0) && (y0 < HH), vy1 = (y1 >= 0) && (y1 < HH);
        bool vx0 = (x0 >= 0) && (x0 < WW), vx1 = (x1 >= 0) && (x1 < WW);
        int yc0 = min(max(y0, 0), HH - 1), yc1 = min(max(y1, 0), HH - 1);
        int xc0 = min(max(x0, 0), WW - 1), xc1 = min(max(x1, 0), WW - 1);
        float v00 = (vy0 && vx0) ? mp[yc0 * WW + xc0] : 0.f;
        float v01 = (vy0 && vx1) ? mp[yc0 * WW + xc1] : 0.f;
        float v10 = (vy1 && vx0) ? mp[yc1 * WW + xc0] : 0.f;
        float v11 = (vy1 && vx1) ? mp[yc1 * WW + xc1] : 0.f;
        sum += v00 * (1 - wy) * (1 - wx) + v01 * (1 - wy) * wx
             + v10 * wy * (1 - wx) + v11 * wy * wx;
    }
    float um = 64.f * sum;
    upd[g] = fminf(fmaxf(um, 0.f), 1.f);
}

// ---------------- main deformable conv ----------------
__global__ __launch_bounds__(256) void deform_main(
    const float* __restrict__ input, const float* __restrict__ off,
    const float* __restrict__ mm, const float* __restrict__ wrep3,
    const float* __restrict__ bias, const float* __restrict__ upd,
    float* __restrict__ out)
{
    int g = blockIdx.x * 256 + threadIdx.x;
    int p = g & (HWSZ - 1);
    int b = g >> 14;
    int i = p >> 7, j = p & 127;

    float acc[64];
#pragma unroll
    for (int o = 0; o < 64; ++o) acc[o] = 0.f;

    const float* xb = input + (size_t)b * CIN * HWSZ;

    for (int k = 0; k < KK; ++k) {
        float dy = off[(b * 18 + 2 * k) * HWSZ + p];
        float dx = off[(b * 18 + 2 * k + 1) * HWSZ + p];
        float m  = mm[(b * 9 + k) * HWSZ + p];
        float py = dy + (float)(k / 3 + i - 1);
        float px = dx + (float)(k % 3 + j - 1);
        float fy = floorf(py), fx = floorf(px);
        float wy = py - fy, wx = px - fx;
        int y0 = (int)fy, x0 = (int)fx;
        int y1 = y0 + 1, x1 = x0 + 1;
        bool vy0 = (y0 >= 0) && (y0 < HH), vy1 = (y1 >= 0) && (y1 < HH);
        bool vx0 = (x0 >= 0) && (x0 < WW), vx1 = (x1 >= 0) && (x1 < WW);
        int yc0 = min(max(y0, 0), HH - 1), yc1 = min(max(y1, 0), HH - 1);
        int xc0 = min(max(x0, 0), WW - 1), xc1 = min(max(x1, 0), WW - 1);
        float w00 = (vy0 && vx0) ? (1 - wy) * (1 - wx) * m : 0.f;
        float w01 = (vy0 && vx1) ? (1 - wy) * wx * m : 0.f;
        float w10 = (vy1 && vx0) ? wy * (1 - wx) * m : 0.f;
        float w11 = (vy1 && vx1) ? wy * wx * m : 0.f;
        int i00 = yc0 * WW + xc0, i01 = yc0 * WW + xc1;
        int i10 = yc1 * WW + xc0, i11 = yc1 * WW + xc1;

        const float* wk = wrep3 + k * 64 * 64;

        // software-pipelined gather over channels
        float n00 = xb[i00], n01 = xb[i01], n10 = xb[i10], n11 = xb[i11];
        for (int c = 0; c < CIN; ++c) {
            float v00 = n00, v01 = n01, v10 = n10, v11 = n11;
            if (c + 1 < CIN) {
                const float* xp = xb + (size_t)(c + 1) * HWSZ;
                n00 = xp[i00]; n01 = xp[i01]; n10 = xp[i10]; n11 = xp[i11];
            }
            float val = fmaf(w00, v00, fmaf(w01, v01, fmaf(w10, v10, w11 * v11)));
            const float* wc = wk + c * 64;
#pragma unroll
            for (int o = 0; o < 64; ++o)
                acc[o] = fmaf(val, wc[o], acc[o]);
        }
    }

    float u = upd[g];
#pragma unroll
    for (int o = 0; o < 64; ++o)
        out[((b * 64 + o) * HWSZ) + p] = (acc[o] + bias[o]) * u;
}

extern "C" void kernel_launch(void* const* d_in, const int* in_sizes, int n_in,
                              void* d_out, int out_size, void* d_ws, size_t ws_size,
                              hipStream_t stream) {
    const float* input    = (const float*)d_in[0];
    const float* mask_in  = (const float*)d_in[1];
    const float* weight   = (const float*)d_in[2];
    const float* bias     = (const float*)d_in[3];
    const float* offset_w = (const float*)d_in[4];
    const float* offset_b = (const float*)d_in[5];
    const float* mask_w   = (const float*)d_in[6];
    const float* mask_b   = (const float*)d_in[7];

    float* out = (float*)d_out;
    float* upd = out + (size_t)NB * COUT * HWSZ;  // update_mask output segment

    float* ws = (float*)d_ws;
    float* off_ws = ws;                          // NB*18*HWSZ
    float* mm_ws  = off_ws + (size_t)NB * 18 * HWSZ;  // NB*9*HWSZ
    float* wrep1  = mm_ws + (size_t)NB * 9 * HWSZ;    // 65*9*27
    float* wrep3  = wrep1 + 65 * 9 * 27;              // 9*64*64

    hipLaunchKernelGGL(repack_kernel, dim3(144), dim3(256), 0, stream,
                       offset_w, mask_w, weight, wrep1, wrep3);
    hipLaunchKernelGGL(conv_offset_mask, dim3(256), dim3(256), 0, stream,
                       input, mask_in, wrep1, offset_b, mask_b, off_ws, mm_ws);
    hipLaunchKernelGGL(update_mask_kernel, dim3(256), dim3(256), 0, stream,
                       mask_in, off_ws, upd);
    hipLaunchKernelGGL(deform_main, dim3(256), dim3(256), 0, stream,
                       input, off_ws, mm_ws, wrep3, bias, upd, out);
}

// Round 2
// 219.226 us; speedup vs baseline: 2.2407x; 2.2407x over previous
//
#include <hip/hip_runtime.h>

#define HH 128
#define WW 128
#define HWSZ (HH*WW)
#define NB 4
#define CIN 64
#define COUT 64
#define KK 9

typedef short bf16x8 __attribute__((ext_vector_type(8)));
typedef float f32x4 __attribute__((ext_vector_type(4)));

__device__ __forceinline__ short f2bf(float f) {
    union { float f; unsigned u; } v; v.f = f;
    unsigned r = v.u + 0x7FFFu + ((v.u >> 16) & 1u);
    return (short)(r >> 16);
}

// ---------------- weight repack ----------------
// wrep1: [65][9][27] f32  (o: 0..17 = offset_w, 18..26 = mask_w)
// wbf:   bf16 B-fragments for deform GEMM:
//   frag[(tap*2+ks)*4+nt][lane][j] = bf16(weight[o][c][tap])
//   with o = nt*16 + (lane&15), c = ks*32 + ((lane>>4)&3)*8 + j
__global__ void repack_kernel(const float* __restrict__ offset_w,
                              const float* __restrict__ mask_w,
                              const float* __restrict__ weight,
                              float* __restrict__ wrep1,
                              short* __restrict__ wbf) {
    int idx = blockIdx.x * 256 + threadIdx.x;
    if (idx < 65 * 9 * 27) {
        int o = idx % 27;
        int t = (idx / 27) % 9;
        int c = idx / (27 * 9);
        float v = (o < 18) ? offset_w[(o * 65 + c) * 9 + t]
                           : mask_w[((o - 18) * 65 + c) * 9 + t];
        wrep1[idx] = v;
    }
    if (idx < 9 * 2 * 4 * 64 * 8) {
        int j  = idx & 7;
        int l  = (idx >> 3) & 63;
        int nt = (idx >> 9) & 3;
        int ks = (idx >> 11) & 1;
        int tap = idx >> 12;
        int o = nt * 16 + (l & 15);
        int c = ks * 32 + ((l >> 4) & 3) * 8 + j;
        wbf[idx] = f2bf(weight[(o * 64 + c) * 9 + tap]);
    }
}

// ---------------- offset + mask conv (65ch in, 27ch out, 3x3, pad 1) ----------------
// 4-way output-channel split for occupancy: group g handles outputs [7g, 7g+7) ∩ [0,27)
__global__ __launch_bounds__(256, 4) void conv_offset_mask(
    const float* __restrict__ input, const float* __restrict__ mask_in,
    const float* __restrict__ wrep1, const float* __restrict__ offset_b,
    const float* __restrict__ mask_b,
    float* __restrict__ off_out, float* __restrict__ mm_out)
{
    int group = blockIdx.x & 3;
    int rest  = blockIdx.x >> 2;
    int tx = threadIdx.x & 15, ty = threadIdx.x >> 4;
    int j = (rest & 7) * 16 + tx;
    int i = ((rest >> 3) & 7) * 16 + ty;
    int b = rest >> 6;
    int obase = group * 7;

    float acc[7];
#pragma unroll
    for (int oo = 0; oo < 7; ++oo) {
        int o = obase + oo;
        acc[oo] = (o < 18) ? offset_b[o] : (o < 27 ? mask_b[o - 18] : 0.f);
    }

    float patch[9];
    {
        const float* xp = input + (size_t)(b * 64) * HWSZ;
#pragma unroll
        for (int dy = 0; dy < 3; ++dy) {
            int yy = i + dy - 1;
#pragma unroll
            for (int dx = 0; dx < 3; ++dx) {
                int xx = j + dx - 1;
                bool ok = (yy >= 0) && (yy < HH) && (xx >= 0) && (xx < WW);
                patch[dy * 3 + dx] = ok ? xp[yy * WW + xx] : 0.f;
            }
        }
    }

    for (int c = 0; c < 65; ++c) {
        float cur[9];
#pragma unroll
        for (int t = 0; t < 9; ++t) cur[t] = patch[t];
        if (c < 64) {
            const float* xp = (c + 1 < 64) ? (input + (size_t)(b * 64 + c + 1) * HWSZ)
                                           : (mask_in + (size_t)b * HWSZ);
#pragma unroll
            for (int dy = 0; dy < 3; ++dy) {
                int yy = i + dy - 1;
#pragma unroll
                for (int dx = 0; dx < 3; ++dx) {
                    int xx = j + dx - 1;
                    bool ok = (yy >= 0) && (yy < HH) && (xx >= 0) && (xx < WW);
                    patch[dy * 3 + dx] = ok ? xp[yy * WW + xx] : 0.f;
                }
            }
        }
        const float* wp = wrep1 + c * 243 + obase;
#pragma unroll
        for (int t = 0; t < 9; ++t) {
            float pv = cur[t];
#pragma unroll
            for (int oo = 0; oo < 7; ++oo)
                acc[oo] = fmaf(pv, wp[t * 27 + oo], acc[oo]);
        }
    }

    int p = i * WW + j;
#pragma unroll
    for (int oo = 0; oo < 7; ++oo) {
        int o = obase + oo;
        if (o < 18) {
            off_out[(b * 18 + o) * HWSZ + p] = acc[oo];
        } else if (o < 27) {
            float s = 1.f / (1.f + __expf(-acc[oo]));
            mm_out[(b * 9 + (o - 18)) * HWSZ + p] = s;
        }
    }
}

// ---------------- update_mask: clip(64 * sum_k bilinear(mask_in), 0, 1) ----------------
__global__ __launch_bounds__(256) void update_mask_kernel(
    const float* __restrict__ mask_in, const float* __restrict__ off,
    float* __restrict__ upd)
{
    int g = blockIdx.x * 256 + threadIdx.x;
    int p = g & (HWSZ - 1);
    int b = g >> 14;
    int i = p >> 7, j = p & 127;
    const float* mp = mask_in + (size_t)b * HWSZ;
    float sum = 0.f;
#pragma unroll
    for (int k = 0; k < KK; ++k) {
        float dy = off[(b * 18 + 2 * k) * HWSZ + p];
        float dx = off[(b * 18 + 2 * k + 1) * HWSZ + p];
        float py = dy + (float)(k / 3 + i - 1);
        float px = dx + (float)(k % 3 + j - 1);
        float fy = floorf(py), fx = floorf(px);
        float wy = py - fy, wx = px - fx;
        int y0 = (int)fy, x0 = (int)fx;
        int y1 = y0 + 1, x1 = x0 + 1;
        bool vy0 = (y0 >= 0) && (y0 < HH), vy1 = (y1 >= 0) && (y1 < HH);
        bool vx0 = (x0 >= 0) && (x0 < WW), vx1 = (x1 >= 0) && (x1 < WW);
        int yc0 = min(max(y0, 0), HH - 1), yc1 = min(max(y1, 0), HH - 1);
        int xc0 = min(max(x0, 0), WW - 1), xc1 = min(max(x1, 0), WW - 1);
        float v00 = (vy0 && vx0) ? mp[yc0 * WW + xc0] : 0.f;
        float v01 = (vy0 && vx1) ? mp[yc0 * WW + xc1] : 0.f;
        float v10 = (vy1 && vx0) ? mp[yc1 * WW + xc0] : 0.f;
        float v11 = (vy1 && vx1) ? mp[yc1 * WW + xc1] : 0.f;
        sum += v00 * (1 - wy) * (1 - wx) + v01 * (1 - wy) * wx
             + v10 * wy * (1 - wx) + v11 * wy * wx;
    }
    float um = 64.f * sum;
    upd[g] = fminf(fmaxf(um, 0.f), 1.f);
}

// ---------------- main deformable conv: MFMA ----------------
// Wave = 16 pixels (M) x 64 out-channels (4 N-tiles). A built on the fly (bf16),
// B preloaded fragments from wbf. K = 9 taps x 64 channels (2 MFMA K-steps/tap).
__global__ __launch_bounds__(256, 4) void deform_main_mfma(
    const float* __restrict__ input, const float* __restrict__ off,
    const float* __restrict__ mm, const bf16x8* __restrict__ wb,
    const float* __restrict__ bias, const float* __restrict__ upd,
    float* __restrict__ out)
{
    int wid  = threadIdx.x >> 6;
    int lane = threadIdx.x & 63;
    int r  = lane & 15;            // A-row: pixel within tile
    int lg = lane >> 4;            // lane group -> k-slot chunk
    int g0 = blockIdx.x * 64 + wid * 16;   // tile base over NB*HWSZ
    int gp = g0 + r;
    int b = gp >> 14;
    int p = gp & (HWSZ - 1);
    int i = p >> 7, j = p & 127;
    const float* xb = input + (size_t)b * CIN * HWSZ;

    f32x4 acc0 = {0.f,0.f,0.f,0.f}, acc1 = {0.f,0.f,0.f,0.f};
    f32x4 acc2 = {0.f,0.f,0.f,0.f}, acc3 = {0.f,0.f,0.f,0.f};

#pragma unroll 1
    for (int k = 0; k < KK; ++k) {
        float dy = off[(b * 18 + 2 * k) * HWSZ + p];
        float dx = off[(b * 18 + 2 * k + 1) * HWSZ + p];
        float m  = mm[(b * 9 + k) * HWSZ + p];
        float py = dy + (float)(k / 3 + i - 1);
        float px = dx + (float)(k % 3 + j - 1);
        float fy = floorf(py), fx = floorf(px);
        float wy = py - fy, wx = px - fx;
        int y0 = (int)fy, x0 = (int)fx;
        int y1 = y0 + 1, x1 = x0 + 1;
        bool vy0 = (y0 >= 0) && (y0 < HH), vy1 = (y1 >= 0) && (y1 < HH);
        bool vx0 = (x0 >= 0) && (x0 < WW), vx1 = (x1 >= 0) && (x1 < WW);
        int yc0 = min(max(y0, 0), HH - 1), yc1 = min(max(y1, 0), HH - 1);
        int xc0 = min(max(x0, 0), WW - 1), xc1 = min(max(x1, 0), WW - 1);
        float w00 = (vy0 && vx0) ? (1 - wy) * (1 - wx) * m : 0.f;
        float w01 = (vy0 && vx1) ? (1 - wy) * wx * m : 0.f;
        float w10 = (vy1 && vx0) ? wy * (1 - wx) * m : 0.f;
        float w11 = (vy1 && vx1) ? wy * wx * m : 0.f;
        int i00 = yc0 * WW + xc0, i01 = yc0 * WW + xc1;
        int i10 = yc1 * WW + xc0, i11 = yc1 * WW + xc1;

#pragma unroll
        for (int ks = 0; ks < 2; ++ks) {
            const bf16x8* wbk = wb + ((k * 2 + ks) * 4) * 64 + lane;
            bf16x8 B0 = wbk[0];
            bf16x8 B1 = wbk[64];
            bf16x8 B2 = wbk[128];
            bf16x8 B3 = wbk[192];

            const float* xc = xb + (size_t)(ks * 32 + lg * 8) * HWSZ;
            float v[8];
#pragma unroll
            for (int jj = 0; jj < 8; ++jj) {
                const float* xp = xc + (size_t)jj * HWSZ;
                float v00 = xp[i00], v01 = xp[i01], v10 = xp[i10], v11 = xp[i11];
                v[jj] = fmaf(w00, v00, fmaf(w01, v01, fmaf(w10, v10, w11 * v11)));
            }
            bf16x8 A;
#pragma unroll
            for (int jj = 0; jj < 8; ++jj) A[jj] = f2bf(v[jj]);

            acc0 = __builtin_amdgcn_mfma_f32_16x16x32_bf16(A, B0, acc0, 0, 0, 0);
            acc1 = __builtin_amdgcn_mfma_f32_16x16x32_bf16(A, B1, acc1, 0, 0, 0);
            acc2 = __builtin_amdgcn_mfma_f32_16x16x32_bf16(A, B2, acc2, 0, 0, 0);
            acc3 = __builtin_amdgcn_mfma_f32_16x16x32_bf16(A, B3, acc3, 0, 0, 0);
        }
    }

    // Epilogue: C/D layout col = lane&15 (out-channel), row = (lane>>4)*4 + reg (pixel)
    int oc = lane & 15;
    int pr0 = lg * 4;
    float u[4];
#pragma unroll
    for (int rr = 0; rr < 4; ++rr) u[rr] = upd[g0 + pr0 + rr];

#define STORE_NT(ACC, NT)                                                     \
    {                                                                         \
        float bo = bias[(NT) * 16 + oc];                                      \
        _Pragma("unroll")                                                     \
        for (int rr = 0; rr < 4; ++rr) {                                      \
            int gg = g0 + pr0 + rr;                                           \
            int bb = gg >> 14;                                                \
            int pp = gg & (HWSZ - 1);                                         \
            out[((size_t)(bb * 64 + (NT) * 16 + oc)) * HWSZ + pp] =           \
                (ACC[rr] + bo) * u[rr];                                       \
        }                                                                     \
    }
    STORE_NT(acc0, 0)
    STORE_NT(acc1, 1)
    STORE_NT(acc2, 2)
    STORE_NT(acc3, 3)
#undef STORE_NT
}

extern "C" void kernel_launch(void* const* d_in, const int* in_sizes, int n_in,
                              void* d_out, int out_size, void* d_ws, size_t ws_size,
                              hipStream_t stream) {
    const float* input    = (const float*)d_in[0];
    const float* mask_in  = (const float*)d_in[1];
    const float* weight   = (const float*)d_in[2];
    const float* bias     = (const float*)d_in[3];
    const float* offset_w = (const float*)d_in[4];
    const float* offset_b = (const float*)d_in[5];
    const float* mask_w   = (const float*)d_in[6];
    const float* mask_b   = (const float*)d_in[7];

    float* out = (float*)d_out;
    float* upd = out + (size_t)NB * COUT * HWSZ;

    float* ws = (float*)d_ws;
    float* off_ws = ws;                                    // NB*18*HWSZ
    float* mm_ws  = off_ws + (size_t)NB * 18 * HWSZ;       // NB*9*HWSZ
    float* wrep1  = mm_ws + (size_t)NB * 9 * HWSZ;         // 15795 (+pad to 15872)
    short* wbf    = (short*)(wrep1 + 15872);               // 36864 bf16, 16B-aligned

    hipLaunchKernelGGL(repack_kernel, dim3(144), dim3(256), 0, stream,
                       offset_w, mask_w, weight, wrep1, wbf);
    hipLaunchKernelGGL(conv_offset_mask, dim3(1024), dim3(256), 0, stream,
                       input, mask_in, wrep1, offset_b, mask_b, off_ws, mm_ws);
    hipLaunchKernelGGL(update_mask_kernel, dim3(256), dim3(256), 0, stream,
                       mask_in, off_ws, upd);
    hipLaunchKernelGGL(deform_main_mfma, dim3(1024), dim3(256), 0, stream,
                       input, off_ws, mm_ws, (const bf16x8*)wbf, bias, upd, out);
}

// Round 3
// 63.577 us; speedup vs baseline: 7.7265x; 3.4482x over previous
//
#include <hip/hip_runtime.h>

#define HH 128
#define WW 128
#define HWSZ (HH*WW)
#define NB 4
#define CIN 64
#define COUT 64
#define KK 9
#define XSTR 72   // NHWC channel stride in bf16 elements (144 B, 16B-aligned)

typedef short bf16x8 __attribute__((ext_vector_type(8)));
typedef float f32x4 __attribute__((ext_vector_type(4)));

union U4 { uint4 v; unsigned a[4]; };

__device__ __forceinline__ short f2bf(float f) {
    union { float f; unsigned u; } v; v.f = f;
    unsigned r = v.u + 0x7FFFu + ((v.u >> 16) & 1u);
    return (short)(r >> 16);
}
__device__ __forceinline__ float bflo(unsigned dw) {
    union { unsigned u; float f; } v; v.u = dw << 16; return v.f;
}
__device__ __forceinline__ float bfhi(unsigned dw) {
    union { unsigned u; float f; } v; v.u = dw & 0xFFFF0000u; return v.f;
}
__device__ __forceinline__ unsigned cvtpk(float lo, float hi) {
    unsigned r;
    asm("v_cvt_pk_bf16_f32 %0, %1, %2" : "=v"(r) : "v"(lo), "v"(hi));
    return r;
}

// ---------------- prep: NHWC-bf16 transpose (blocks 0..1023) + weight repack ----------------
// xt: [NB*HWSZ][XSTR] bf16, channels 0..63 real, 64..71 zero pad
// wd: deform B frags  [(tap*2+ks)*4+nt][64][8]
// wc: conv   B frags  [(tap*2+ks)*2+nt][64][8]
// wmf: f32 [tap][nt][64]: conv weight for input mask channel (c=64)
__global__ __launch_bounds__(256) void prep_kernel(
    const float* __restrict__ input,
    const float* __restrict__ weight,
    const float* __restrict__ offset_w,
    const float* __restrict__ mask_w,
    short* __restrict__ xt,
    short* __restrict__ wd,
    short* __restrict__ wc,
    float* __restrict__ wmf)
{
    __shared__ short lds[64 * 80];
    int bid = blockIdx.x;
    if (bid < 1024) {
        int g0 = bid * 64;
        int b  = g0 >> 14;
        int p0 = g0 & (HWSZ - 1);
        int px = threadIdx.x & 63;
        int cq = threadIdx.x >> 6;
#pragma unroll
        for (int it = 0; it < 16; ++it) {
            int c = it * 4 + cq;
            float v = input[((size_t)(b * 64 + c)) * HWSZ + p0 + px];
            lds[px * 80 + c] = f2bf(v);
        }
#pragma unroll
        for (int it = 0; it < 2; ++it) {
            int c = 64 + it * 4 + cq;
            lds[px * 80 + c] = 0;
        }
        __syncthreads();
#pragma unroll
        for (int it = 0; it < 3; ++it) {
            int idx = it * 256 + threadIdx.x;
            if (idx < 576) {
                int ppx = idx / 9, s = idx - ppx * 9;
                bf16x8 v = *(const bf16x8*)&lds[ppx * 80 + s * 8];
                *(bf16x8*)&xt[((size_t)(g0 + ppx)) * XSTR + s * 8] = v;
            }
        }
    } else {
        int idx = (bid - 1024) * 256 + threadIdx.x;   // 0..36863
        if (idx < 36864) {
            int j  = idx & 7;
            int l  = (idx >> 3) & 63;
            int nt = (idx >> 9) & 3;
            int ks = (idx >> 11) & 1;
            int tap = idx >> 12;
            int o = nt * 16 + (l & 15);
            int c = ks * 32 + ((l >> 4) & 3) * 8 + j;
            wd[idx] = f2bf(weight[(o * 64 + c) * 9 + tap]);
        }
        if (idx < 18432) {
            int j  = idx & 7;
            int l  = (idx >> 3) & 63;
            int nt = (idx >> 9) & 1;
            int ks = (idx >> 10) & 1;
            int tap = idx >> 11;
            int o = nt * 16 + (l & 15);
            int c = ks * 32 + ((l >> 4) & 3) * 8 + j;
            float v = 0.f;
            if (o < 18)      v = offset_w[(o * 65 + c) * 9 + tap];
            else if (o < 27) v = mask_w[((o - 18) * 65 + c) * 9 + tap];
            wc[idx] = f2bf(v);
        }
        if (idx < 1152) {
            int l  = idx & 63;
            int nt = (idx >> 6) & 1;
            int tap = idx >> 7;
            int o = nt * 16 + (l & 15);
            float v = 0.f;
            if (o < 18)      v = offset_w[(o * 65 + 64) * 9 + tap];
            else if (o < 27) v = mask_w[((o - 18) * 65 + 64) * 9 + tap];
            wmf[idx] = v;
        }
    }
}

// ---------------- conv (65ch in, 27ch out, 3x3, pad 1) via MFMA ----------------
__global__ __launch_bounds__(256, 4) void conv_offset_mfma(
    const short* __restrict__ xt, const float* __restrict__ mask_in,
    const bf16x8* __restrict__ wc, const float* __restrict__ wmf,
    const float* __restrict__ offset_b, const float* __restrict__ mask_b,
    float* __restrict__ off_out, float* __restrict__ mm_out)
{
    int wid = threadIdx.x >> 6;
    int lane = threadIdx.x & 63;
    int r = lane & 15, lg = lane >> 4;
    int g0 = blockIdx.x * 64 + wid * 16;
    int gp = g0 + r;
    int b = gp >> 14, p = gp & (HWSZ - 1);
    int i = p >> 7, j = p & 127;
    const short* xb = xt + ((size_t)(b << 14)) * XSTR;

    f32x4 acc0 = {0,0,0,0}, acc1 = {0,0,0,0};

#pragma unroll
    for (int t = 0; t < 9; ++t) {
        int yy = i + t / 3 - 1, xx = j + t % 3 - 1;
        bool valid = ((unsigned)yy < HH) && ((unsigned)xx < WW);
        int nb = yy * WW + xx;
        const short* ap = xb + (size_t)(valid ? nb : 0) * XSTR + lg * 8;
        const bf16x8* wck = wc + (t * 4) * 64 + lane;
#pragma unroll
        for (int ks = 0; ks < 2; ++ks) {
            union { bf16x8 s; uint4 u; } A;
            A.u = *(const uint4*)(ap + ks * 32);
            if (!valid) { A.u.x = 0; A.u.y = 0; A.u.z = 0; A.u.w = 0; }
            bf16x8 B0 = wck[(ks * 2 + 0) * 64];
            bf16x8 B1 = wck[(ks * 2 + 1) * 64];
            acc0 = __builtin_amdgcn_mfma_f32_16x16x32_bf16(A.s, B0, acc0, 0, 0, 0);
            acc1 = __builtin_amdgcn_mfma_f32_16x16x32_bf16(A.s, B1, acc1, 0, 0, 0);
        }
    }

    // mask-channel (c=64) contribution in f32
    float m0[4] = {0,0,0,0}, m1[4] = {0,0,0,0};
#pragma unroll
    for (int t = 0; t < 9; ++t) {
        float wv0 = wmf[(t * 2 + 0) * 64 + lane];
        float wv1 = wmf[(t * 2 + 1) * 64 + lane];
#pragma unroll
        for (int rr = 0; rr < 4; ++rr) {
            int gpix = g0 + lg * 4 + rr;
            int pb = gpix >> 14, pp = gpix & (HWSZ - 1);
            int pi = pp >> 7, pj = pp & 127;
            int yy = pi + t / 3 - 1, xx = pj + t % 3 - 1;
            bool v = ((unsigned)yy < HH) && ((unsigned)xx < WW);
            float mv = v ? mask_in[(size_t)pb * HWSZ + yy * WW + xx] : 0.f;
            m0[rr] = fmaf(mv, wv0, m0[rr]);
            m1[rr] = fmaf(mv, wv1, m1[rr]);
        }
    }

    int oc0 = lane & 15;
    {   // nt = 0: oc = 0..15, all offsets
        float bo = offset_b[oc0];
#pragma unroll
        for (int rr = 0; rr < 4; ++rr) {
            int gpix = g0 + lg * 4 + rr;
            int pb = gpix >> 14, pp = gpix & (HWSZ - 1);
            off_out[((size_t)(pb * 18 + oc0)) * HWSZ + pp] = acc0[rr] + m0[rr] + bo;
        }
    }
    {   // nt = 1: oc = 16..31 (16,17 offsets; 18..26 mask; rest dead)
        int oc = 16 + oc0;
        if (oc < 18) {
            float bo = offset_b[oc];
#pragma unroll
            for (int rr = 0; rr < 4; ++rr) {
                int gpix = g0 + lg * 4 + rr;
                int pb = gpix >> 14, pp = gpix & (HWSZ - 1);
                off_out[((size_t)(pb * 18 + oc)) * HWSZ + pp] = acc1[rr] + m1[rr] + bo;
            }
        } else if (oc < 27) {
            float bo = mask_b[oc - 18];
#pragma unroll
            for (int rr = 0; rr < 4; ++rr) {
                int gpix = g0 + lg * 4 + rr;
                int pb = gpix >> 14, pp = gpix & (HWSZ - 1);
                float z = acc1[rr] + m1[rr] + bo;
                mm_out[((size_t)(pb * 9 + (oc - 18))) * HWSZ + pp] =
                    1.f / (1.f + __expf(-z));
            }
        }
    }
}

// ---------------- main deformable conv: MFMA + fused update_mask ----------------
__global__ __launch_bounds__(256, 4) void deform_main_mfma(
    const short* __restrict__ xt, const float* __restrict__ off,
    const float* __restrict__ mm, const float* __restrict__ mask_in,
    const bf16x8* __restrict__ wd, const float* __restrict__ bias,
    float* __restrict__ out, float* __restrict__ upd)
{
    int wid = threadIdx.x >> 6, lane = threadIdx.x & 63;
    int r = lane & 15, lg = lane >> 4;
    int g0 = blockIdx.x * 64 + wid * 16;
    int gp = g0 + r;
    int b = gp >> 14, p = gp & (HWSZ - 1);
    int i = p >> 7, j = p & 127;
    const short* xb = xt + ((size_t)(b << 14)) * XSTR;
    const float* mb = mask_in + (size_t)b * HWSZ;

    f32x4 acc0 = {0,0,0,0}, acc1 = {0,0,0,0}, acc2 = {0,0,0,0}, acc3 = {0,0,0,0};
    float um = 0.f;

#pragma unroll 1
    for (int k = 0; k < KK; ++k) {
        float dy = off[(b * 18 + 2 * k) * HWSZ + p];
        float dx = off[(b * 18 + 2 * k + 1) * HWSZ + p];
        float m  = mm[(b * 9 + k) * HWSZ + p];
        float py = dy + (float)(k / 3 + i - 1);
        float px = dx + (float)(k % 3 + j - 1);
        float fy = floorf(py), fx = floorf(px);
        float wy = py - fy, wx = px - fx;
        int y0 = (int)fy, x0 = (int)fx;
        int y1 = y0 + 1, x1 = x0 + 1;
        bool vy0 = (unsigned)y0 < HH, vy1 = (unsigned)y1 < HH;
        bool vx0 = (unsigned)x0 < WW, vx1 = (unsigned)x1 < WW;
        int yc0 = min(max(y0, 0), HH - 1), yc1 = min(max(y1, 0), HH - 1);
        int xc0 = min(max(x0, 0), WW - 1), xc1 = min(max(x1, 0), WW - 1);
        float r00 = (vy0 && vx0) ? (1 - wy) * (1 - wx) : 0.f;
        float r01 = (vy0 && vx1) ? (1 - wy) * wx : 0.f;
        float r10 = (vy1 && vx0) ? wy * (1 - wx) : 0.f;
        float r11 = (vy1 && vx1) ? wy * wx : 0.f;
        int i00 = yc0 * WW + xc0, i01 = yc0 * WW + xc1;
        int i10 = yc1 * WW + xc0, i11 = yc1 * WW + xc1;

        // fused update_mask accumulation (no dcn-mask factor)
        um += r00 * mb[i00] + r01 * mb[i01] + r10 * mb[i10] + r11 * mb[i11];

        float w00 = r00 * m, w01 = r01 * m, w10 = r10 * m, w11 = r11 * m;

        const uint4* a00 = (const uint4*)(xb + (size_t)i00 * XSTR + lg * 8);
        const uint4* a01 = (const uint4*)(xb + (size_t)i01 * XSTR + lg * 8);
        const uint4* a10 = (const uint4*)(xb + (size_t)i10 * XSTR + lg * 8);
        const uint4* a11 = (const uint4*)(xb + (size_t)i11 * XSTR + lg * 8);
        const bf16x8* wbk = wd + (k * 8) * 64 + lane;

#pragma unroll
        for (int ks = 0; ks < 2; ++ks) {
            U4 c00, c01, c10, c11;
            c00.v = a00[ks * 4];
            c01.v = a01[ks * 4];
            c10.v = a10[ks * 4];
            c11.v = a11[ks * 4];
            union { bf16x8 s; unsigned u[4]; } A;
#pragma unroll
            for (int q = 0; q < 4; ++q) {
                unsigned d00 = c00.a[q], d01 = c01.a[q], d10 = c10.a[q], d11 = c11.a[q];
                float vlo = fmaf(w00, bflo(d00), fmaf(w01, bflo(d01),
                            fmaf(w10, bflo(d10), w11 * bflo(d11))));
                float vhi = fmaf(w00, bfhi(d00), fmaf(w01, bfhi(d01),
                            fmaf(w10, bfhi(d10), w11 * bfhi(d11))));
                A.u[q] = cvtpk(vlo, vhi);
            }
            bf16x8 B0 = wbk[(ks * 4 + 0) * 64];
            bf16x8 B1 = wbk[(ks * 4 + 1) * 64];
            bf16x8 B2 = wbk[(ks * 4 + 2) * 64];
            bf16x8 B3 = wbk[(ks * 4 + 3) * 64];
            acc0 = __builtin_amdgcn_mfma_f32_16x16x32_bf16(A.s, B0, acc0, 0, 0, 0);
            acc1 = __builtin_amdgcn_mfma_f32_16x16x32_bf16(A.s, B1, acc1, 0, 0, 0);
            acc2 = __builtin_amdgcn_mfma_f32_16x16x32_bf16(A.s, B2, acc2, 0, 0, 0);
            acc3 = __builtin_amdgcn_mfma_f32_16x16x32_bf16(A.s, B3, acc3, 0, 0, 0);
        }
    }

    um = fminf(fmaxf(64.f * um, 0.f), 1.f);
    if (lane < 16) upd[g0 + lane] = um;

    int oc = lane & 15;
    int pr0 = lg * 4;
    float u[4];
#pragma unroll
    for (int rr = 0; rr < 4; ++rr) u[rr] = __shfl(um, pr0 + rr, 64);

#define STORE_NT(ACC, NT)                                                     \
    {                                                                         \
        float bo = bias[(NT) * 16 + oc];                                      \
        _Pragma("unroll")                                                     \
        for (int rr = 0; rr < 4; ++rr) {                                      \
            int gg = g0 + pr0 + rr;                                           \
            int bb = gg >> 14;                                                \
            int pp = gg & (HWSZ - 1);                                         \
            out[((size_t)(bb * 64 + (NT) * 16 + oc)) * HWSZ + pp] =           \
                (ACC[rr] + bo) * u[rr];                                       \
        }                                                                     \
    }
    STORE_NT(acc0, 0)
    STORE_NT(acc1, 1)
    STORE_NT(acc2, 2)
    STORE_NT(acc3, 3)
#undef STORE_NT
}

extern "C" void kernel_launch(void* const* d_in, const int* in_sizes, int n_in,
                              void* d_out, int out_size, void* d_ws, size_t ws_size,
                              hipStream_t stream) {
    const float* input    = (const float*)d_in[0];
    const float* mask_in  = (const float*)d_in[1];
    const float* weight   = (const float*)d_in[2];
    const float* bias     = (const float*)d_in[3];
    const float* offset_w = (const float*)d_in[4];
    const float* offset_b = (const float*)d_in[5];
    const float* mask_w   = (const float*)d_in[6];
    const float* mask_b   = (const float*)d_in[7];

    float* out = (float*)d_out;
    float* upd = out + (size_t)NB * COUT * HWSZ;

    float* ws = (float*)d_ws;
    float* off_ws = ws;                                       // 1,179,648 f
    float* mm_ws  = off_ws + (size_t)NB * 18 * HWSZ;          //   589,824 f
    float* wmf    = mm_ws + (size_t)NB * 9 * HWSZ;            //     1,152 f
    short* wd     = (short*)(wmf + 1152);                     //    36,864 bf16
    short* wc     = wd + 36864;                               //    18,432 bf16
    short* xt     = wc + 18432;                               // 4,718,592 bf16

    hipLaunchKernelGGL(prep_kernel, dim3(1168), dim3(256), 0, stream,
                       input, weight, offset_w, mask_w, xt, wd, wc, wmf);
    hipLaunchKernelGGL(conv_offset_mfma, dim3(1024), dim3(256), 0, stream,
                       xt, mask_in, (const bf16x8*)wc, wmf, offset_b, mask_b,
                       off_ws, mm_ws);
    hipLaunchKernelGGL(deform_main_mfma, dim3(1024), dim3(256), 0, stream,
                       xt, off_ws, mm_ws, mask_in, (const bf16x8*)wd, bias,
                       out, upd);
}